// Round 2
// baseline (341.644 us; speedup 1.0000x reference)
//
#include <hip/hip_runtime.h>

// Problem constants: B=4, S=256, V=50257, D=768
#define VOCAB 50257
#define DIM   768

constexpr int ROWS    = 1024;                        // B*S
constexpr int TOTAL4  = ROWS * (VOCAB / 4) + ROWS / 4; // careful: do exact below
// Exact: ROWS*VOCAB = 51,463,168 floats; /4 = 12,865,792 float4s (fits in int32)
constexpr int TOTAL4_EXACT = 12865792;
constexpr int F4_PER_THREAD = 16;                    // 256 B per thread
constexpr int BLOCK = 256;
constexpr int F4_PER_BLOCK = BLOCK * F4_PER_THREAD;  // 4096
constexpr int NBLOCKS = (TOTAL4_EXACT + F4_PER_BLOCK - 1) / F4_PER_BLOCK; // 3142
constexpr int DIM4 = DIM / 4;                        // 192

// Kernel 1: scan one_hot (as raw uint4) for the single nonzero per row.
// Each thread OR-reduces 16 block-strided float4s (fully coalesced per wave:
// iteration k reads a contiguous 4 KB slab per block). Hit path (rare, ~8% of
// waves) reloads and locates the column; writes idx[row] = col.
__global__ __launch_bounds__(BLOCK) void find_idx_kernel(
    const uint4* __restrict__ oh, int* __restrict__ idx) {
    const int base = blockIdx.x * F4_PER_BLOCK + threadIdx.x;

    unsigned acc = 0;
    #pragma unroll
    for (int k = 0; k < F4_PER_THREAD; ++k) {
        int i = base + k * BLOCK;
        if (i < TOTAL4_EXACT) {
            uint4 t = oh[i];
            acc |= t.x | t.y | t.z | t.w;
        }
    }

    if (acc != 0) {
        // Rare path: reload and locate. A thread's 16 vectors may contain up
        // to two hits (region straddles a row boundary) -> check all.
        #pragma unroll 1
        for (int k = 0; k < F4_PER_THREAD; ++k) {
            int i = base + k * BLOCK;
            if (i >= TOTAL4_EXACT) break;
            uint4 t = oh[i];
            unsigned a[4] = {t.x, t.y, t.z, t.w};
            #pragma unroll
            for (int j = 0; j < 4; ++j) {
                if (a[j] != 0u) {
                    long flat = (long)i * 4 + j;
                    int row = (int)(flat / VOCAB);
                    int col = (int)(flat - (long)row * VOCAB);
                    idx[row] = col;
                }
            }
        }
    }
}

// Kernel 2: gather weight[idx[row]] -> out[row], float4-coalesced.
__global__ __launch_bounds__(DIM4) void gather_kernel(
    const float4* __restrict__ weight, const int* __restrict__ idx,
    float4* __restrict__ out) {
    int row = blockIdx.x;
    int t   = threadIdx.x;            // 0..191
    int src = idx[row];
    out[row * DIM4 + t] = weight[(long)src * DIM4 + t];
}

extern "C" void kernel_launch(void* const* d_in, const int* in_sizes, int n_in,
                              void* d_out, int out_size, void* d_ws, size_t ws_size,
                              hipStream_t stream) {
    const uint4*  one_hot = (const uint4*)d_in[0];    // [B,S,V] f32 (raw bits)
    const float4* weight  = (const float4*)d_in[1];   // [V,D]  f32
    float4* out = (float4*)d_out;                     // [B,S,D] f32
    int* idx = (int*)d_ws;                            // ROWS ints of scratch

    find_idx_kernel<<<NBLOCKS, BLOCK, 0, stream>>>(one_hot, idx);
    gather_kernel<<<ROWS, DIM4, 0, stream>>>(weight, idx, out);
}